// Round 1
// baseline (26533.289 us; speedup 1.0000x reference)
//
#include <hip/hip_runtime.h>
#include <math.h>

#define TSTEPS 512
#define BATCH 64
#define IDIM 128
#define HDIM 1024

// Zero the 4 transposed-state ping-pong buffers (2 layers x 2) at the start of
// every launch (harness poisons ws; launch must be deterministic).
__global__ void init_ws_kernel(float* __restrict__ ws) {
    int i = blockIdx.x * blockDim.x + threadIdx.x;
    const int total = 4 * HDIM * BATCH;
    for (; i < total; i += gridDim.x * blockDim.x) ws[i] = 0.0f;
}

// Pipeline-skewed step kernel.
// blocks 0..255  : layer 0, step t = i        (valid when i < TSTEPS)
// blocks 256..511: layer 1, step s = i - 1    (valid when i >= 1)
// State is stored transposed: hT[j][b], so lane (=b) reads are coalesced.
__global__ __launch_bounds__(256) void step_kernel(
    int i,
    const float* __restrict__ x,
    const float* __restrict__ Win0, const float* __restrict__ Wh0,
    const float* __restrict__ Win1, const float* __restrict__ Wh1,
    float* __restrict__ out, float* __restrict__ ws)
{
    const int bid = blockIdx.x;
    const int b   = (int)(threadIdx.x & 63);
    // j-group is constant within a wave -> force scalar so W loads become s_load
    const int jq  = __builtin_amdgcn_readfirstlane((int)(threadIdx.x >> 6));

    float* h0T0 = ws;
    float* h0T1 = ws + 1 * HDIM * BATCH;
    float* h1T0 = ws + 2 * HDIM * BATCH;
    float* h1T1 = ws + 3 * HDIM * BATCH;

    if (bid < 256) {
        // ----- layer 0, step t -----
        const int t = i;
        if (t >= TSTEPS) return;
        const int j = bid * 4 + jq;
        const float* __restrict__ hR = (t & 1) ? h0T1 : h0T0;
        float* __restrict__       hW = (t & 1) ? h0T0 : h0T1;

        const float* __restrict__ xr = x + ((size_t)t * BATCH + b) * IDIM;
        const float* __restrict__ wi = Win0 + (size_t)j * IDIM;
        const float* __restrict__ wh = Wh0 + (size_t)j * HDIM;

        float a0 = 0.f, a1 = 0.f, a2 = 0.f, a3 = 0.f;
        #pragma unroll 8
        for (int k = 0; k < IDIM; k += 4) {
            float4 xv = *(const float4*)(xr + k);
            a0 += xv.x * wi[k + 0];
            a1 += xv.y * wi[k + 1];
            a2 += xv.z * wi[k + 2];
            a3 += xv.w * wi[k + 3];
        }
        #pragma unroll 8
        for (int k = 0; k < HDIM; k += 4) {
            a0 += hR[(k + 0) * BATCH + b] * wh[k + 0];
            a1 += hR[(k + 1) * BATCH + b] * wh[k + 1];
            a2 += hR[(k + 2) * BATCH + b] * wh[k + 2];
            a3 += hR[(k + 3) * BATCH + b] * wh[k + 3];
        }
        const float pre  = (a0 + a1) + (a2 + a3);
        const float hold = hR[j * BATCH + b];
        const float hnew = 0.5f * hold + 0.5f * tanhf(pre);
        hW[j * BATCH + b] = hnew;
        out[(((size_t)t * BATCH + b) * 2 + 0) * HDIM + j] = hnew;
    } else {
        // ----- layer 1, step s -----
        const int s = i - 1;
        if (s < 0) return;
        const int j = (bid - 256) * 4 + jq;
        const float* __restrict__ hR = (s & 1) ? h1T1 : h1T0;
        float* __restrict__       hW = (s & 1) ? h1T0 : h1T1;

        // layer-1 input = e0[s][b][:] read from d_out (written by kernel i-1)
        const float* __restrict__ xr = out + (((size_t)s * BATCH + b) * 2 + 0) * HDIM;
        const float* __restrict__ wi = Win1 + (size_t)j * HDIM;
        const float* __restrict__ wh = Wh1 + (size_t)j * HDIM;

        float a0 = 0.f, a1 = 0.f, a2 = 0.f, a3 = 0.f;
        #pragma unroll 8
        for (int k = 0; k < HDIM; k += 4) {
            float4 xv = *(const float4*)(xr + k);
            a0 += xv.x * wi[k + 0];
            a1 += xv.y * wi[k + 1];
            a2 += xv.z * wi[k + 2];
            a3 += xv.w * wi[k + 3];
        }
        #pragma unroll 8
        for (int k = 0; k < HDIM; k += 4) {
            a0 += hR[(k + 0) * BATCH + b] * wh[k + 0];
            a1 += hR[(k + 1) * BATCH + b] * wh[k + 1];
            a2 += hR[(k + 2) * BATCH + b] * wh[k + 2];
            a3 += hR[(k + 3) * BATCH + b] * wh[k + 3];
        }
        const float pre  = (a0 + a1) + (a2 + a3);
        const float hold = hR[j * BATCH + b];
        const float hnew = 0.5f * hold + 0.5f * tanhf(pre);
        hW[j * BATCH + b] = hnew;
        out[(((size_t)s * BATCH + b) * 2 + 1) * HDIM + j] = hnew;
    }
}

extern "C" void kernel_launch(void* const* d_in, const int* in_sizes, int n_in,
                              void* d_out, int out_size, void* d_ws, size_t ws_size,
                              hipStream_t stream) {
    const float* x    = (const float*)d_in[0];
    const float* Win0 = (const float*)d_in[1];
    const float* Wh0  = (const float*)d_in[2];
    const float* Win1 = (const float*)d_in[3];
    const float* Wh1  = (const float*)d_in[4];
    float* out = (float*)d_out;
    float* ws  = (float*)d_ws;

    init_ws_kernel<<<64, 256, 0, stream>>>(ws);
    for (int i = 0; i <= TSTEPS; ++i) {
        step_kernel<<<512, 256, 0, stream>>>(i, x, Win0, Wh0, Win1, Wh1, out, ws);
    }
}

// Round 2
// 10628.712 us; speedup vs baseline: 2.4964x; 2.4964x over previous
//
#include <hip/hip_runtime.h>
#include <math.h>

#define TSTEPS 512
#define BATCH  64
#define IDIM   128
#define HDIM   1024
#define JB     8              // output j-columns per block (register reuse factor)
#define NBLK   128            // blocks per layer; NBLK*JB == HDIM
#define NWAVE  8              // waves per block (512 threads)
#define HKW    (HDIM / NWAVE) // h-dim k-slice per wave

// ws layout: 4 state buffers [HDIM][BATCH] fp32 (layer0 ping/pong, layer1 ping/pong)
__global__ void init_ws_kernel(float* __restrict__ ws) {
    int i = blockIdx.x * blockDim.x + threadIdx.x;
    const int total = 4 * HDIM * BATCH;
    for (; i < total; i += gridDim.x * blockDim.x) ws[i] = 0.0f;
}

// Pipeline-skewed step kernel.
// blocks 0..127  : layer 0, step t = i       (valid while t < TSTEPS)
// blocks 128..255: layer 1, step t = i - 1   (valid while t >= 0)
// State stored transposed hT[k][b] so recurrent reads are lane-coalesced.
// Each block computes a [BATCH x JB] output tile; waves split K; weights are
// wave-uniform -> scalar loads; accumulators give 8 FMAs per loaded element.
__global__ __launch_bounds__(512) void step_kernel(
    int i,
    const float* __restrict__ x,
    const float* __restrict__ Wi0, const float* __restrict__ Wh0,
    const float* __restrict__ Wi1, const float* __restrict__ Wh1,
    float* __restrict__ out, float* __restrict__ ws)
{
    __shared__ float red[NWAVE * JB * 65];

    const int bid   = blockIdx.x;
    const int layer = (bid >= NBLK) ? 1 : 0;
    const int t     = layer ? (i - 1) : i;
    if (layer ? (t < 0) : (t >= TSTEPS)) return;
    const int blk = layer ? (bid - NBLK) : bid;

    const int tid = (int)threadIdx.x;
    const int b   = tid & 63;
    const int wv  = __builtin_amdgcn_readfirstlane(tid >> 6);  // wave id (scalar)

    float* __restrict__ hR = ws + (size_t)(2 * layer + (t & 1)) * HDIM * BATCH;
    float* __restrict__ hW = ws + (size_t)(2 * layer + ((t + 1) & 1)) * HDIM * BATCH;

    // x-operand: contiguous in k for both layers (layer1 reads e0 rows from out)
    const float* __restrict__ xrow = layer
        ? out + ((size_t)((size_t)t * BATCH + b) * 2 + 0) * HDIM
        : x + ((size_t)t * BATCH + b) * IDIM;
    const int KX = layer ? HDIM : IDIM;
    const float* __restrict__ Wx = (layer ? Wi1 : Wi0) + (size_t)(blk * JB) * KX;
    const float* __restrict__ Wh = (layer ? Wh1 : Wh0) + (size_t)(blk * JB) * HDIM;

    float acc[JB];
    #pragma unroll
    for (int jj = 0; jj < JB; ++jj) acc[jj] = 0.0f;

    // ---- input part: wave wv covers k in [wv*KX/8, (wv+1)*KX/8) ----
    {
        const int kw = KX / NWAVE;
        const int k0 = wv * kw;
        #pragma unroll 8
        for (int k = k0; k < k0 + kw; ++k) {
            const float xv = xrow[k];
            #pragma unroll
            for (int jj = 0; jj < JB; ++jj)
                acc[jj] = fmaf(xv, Wx[(size_t)jj * KX + k], acc[jj]);
        }
    }

    // ---- recurrent part: wave wv covers k in [wv*128, (wv+1)*128) ----
    {
        const int k0 = wv * HKW;
        #pragma unroll 8
        for (int k = k0; k < k0 + HKW; ++k) {
            const float hv = hR[(size_t)k * BATCH + b];   // coalesced 256B/wave
            #pragma unroll
            for (int jj = 0; jj < JB; ++jj)
                acc[jj] = fmaf(hv, Wh[(size_t)jj * HDIM + k], acc[jj]);
        }
    }

    // ---- cross-wave reduction ----
    #pragma unroll
    for (int jj = 0; jj < JB; ++jj)
        red[(wv * JB + jj) * 65 + b] = acc[jj];
    __syncthreads();

    // thread -> (b2, jj2): 8 consecutive lanes share b2 -> 32B-chunk out writes
    const int b2  = tid >> 3;
    const int jj2 = tid & 7;
    float s = 0.0f;
    #pragma unroll
    for (int w2 = 0; w2 < NWAVE; ++w2)
        s += red[(w2 * JB + jj2) * 65 + b2];

    const int j = blk * JB + jj2;
    const float hold = hR[(size_t)j * BATCH + b2];
    const float hnew = 0.5f * hold + 0.5f * tanhf(s);
    hW[(size_t)j * BATCH + b2] = hnew;
    out[((size_t)((size_t)t * BATCH + b2) * 2 + layer) * HDIM + j] = hnew;
}

extern "C" void kernel_launch(void* const* d_in, const int* in_sizes, int n_in,
                              void* d_out, int out_size, void* d_ws, size_t ws_size,
                              hipStream_t stream) {
    const float* x    = (const float*)d_in[0];
    const float* Wi0  = (const float*)d_in[1];
    const float* Wh0  = (const float*)d_in[2];
    const float* Wi1  = (const float*)d_in[3];
    const float* Wh1  = (const float*)d_in[4];
    float* out = (float*)d_out;
    float* ws  = (float*)d_ws;

    init_ws_kernel<<<64, 256, 0, stream>>>(ws);
    for (int i = 0; i <= TSTEPS; ++i) {
        step_kernel<<<2 * NBLK, 512, 0, stream>>>(i, x, Wi0, Wh0, Wi1, Wh1, out, ws);
    }
}

// Round 3
// 10149.166 us; speedup vs baseline: 2.6143x; 1.0472x over previous
//
#include <hip/hip_runtime.h>
#include <math.h>

#define TSTEPS 512
#define BATCH  64
#define IDIM   128
#define HDIM   1024
#define JB     8              // output j-columns per block (register reuse)
#define NBLK   128            // blocks per layer; NBLK*JB == HDIM
#define NWAVE  8              // waves per block (512 threads)
#define HKW    (HDIM / NWAVE) // recurrent k-slice per wave (128)
#define RSTR   72             // padded stride of reduction buffer rows

// ws layout: 4 state buffers [HDIM][BATCH] fp32, transposed ([k][b]):
//   buf0[0], buf0[1] (layer 0 ping/pong), buf1[0], buf1[1] (layer 1)
__global__ void init_ws_kernel(float* __restrict__ ws) {
    int i = blockIdx.x * blockDim.x + threadIdx.x;
    const int total = 4 * HDIM * BATCH;
    for (; i < total; i += gridDim.x * blockDim.x) ws[i] = 0.0f;
}

// Pipeline-skewed step kernel.
// blocks 0..127  : layer 0, step t = i       (valid while t < TSTEPS)
// blocks 128..255: layer 1, step t = i - 1   (valid while t >= 0)
// All sequential-path operand reads are either lane-coalesced [k][b] streams
// (state in ws) or conflict-free LDS (staged x). `out` is write-only.
__global__ __launch_bounds__(512) void step_kernel(
    int i,
    const float* __restrict__ x,
    const float* __restrict__ Wi0, const float* __restrict__ Wh0,
    const float* __restrict__ Wi1, const float* __restrict__ Wh1,
    float* __restrict__ out, float* __restrict__ ws)
{
    __shared__ float red[NWAVE * JB * RSTR]; // 64 rows x 72 (padded)
    __shared__ float xs[IDIM * 65];          // layer-0 x[t], transposed+padded

    const int bid   = blockIdx.x;
    const int layer = (bid >= NBLK) ? 1 : 0;
    const int t     = layer ? (i - 1) : i;
    if (layer ? (t < 0) : (t >= TSTEPS)) return;
    const int blk = layer ? (bid - NBLK) : bid;

    const int tid = (int)threadIdx.x;
    const int b   = tid & 63;
    const int wv  = __builtin_amdgcn_readfirstlane(tid >> 6);

    float* __restrict__ baseL = ws + (size_t)(2 * layer) * HDIM * BATCH;
    const float* __restrict__ hR = baseL + (size_t)(t & 1) * HDIM * BATCH;
    float* __restrict__       hW = baseL + (size_t)((t + 1) & 1) * HDIM * BATCH;

    const float* __restrict__ Wh = (layer ? Wh1 : Wh0) + (size_t)(blk * JB) * HDIM;

    float acc[JB];
    #pragma unroll
    for (int jj = 0; jj < JB; ++jj) acc[jj] = 0.0f;

    if (layer == 0) {
        // ---- stage x[t] (64x128 fp32, 32 KB) into LDS transposed ----
        const float* __restrict__ xsrc = x + (size_t)t * BATCH * IDIM;
        #pragma unroll
        for (int s = 0; s < 16; ++s) {
            const int f  = tid + s * 512;       // coalesced global read
            const int bb = f >> 7, kk = f & 127;
            xs[kk * 65 + bb] = xsrc[f];         // stride-65: conflict-free
        }
        __syncthreads();
        const float* __restrict__ Wx = Wi0 + (size_t)(blk * JB) * IDIM;
        const int k0 = wv * (IDIM / NWAVE);     // 16 k per wave
        #pragma unroll
        for (int k = k0; k < k0 + IDIM / NWAVE; ++k) {
            const float xv = xs[k * 65 + b];    // lane=b stride-1: conflict-free
            #pragma unroll
            for (int jj = 0; jj < JB; ++jj)
                acc[jj] = fmaf(xv, Wx[(size_t)jj * IDIM + k], acc[jj]);
        }
    } else {
        // ---- layer-1 input: e0[t] = layer-0 state buffer (t+1)&1, [k][b] ----
        const float* __restrict__ xT = ws + (size_t)((t + 1) & 1) * HDIM * BATCH;
        const float* __restrict__ Wx = Wi1 + (size_t)(blk * JB) * HDIM;
        const int k0 = wv * HKW;
        #pragma unroll 8
        for (int k = k0; k < k0 + HKW; ++k) {
            const float xv = xT[(size_t)k * BATCH + b];  // coalesced 256B/wave
            #pragma unroll
            for (int jj = 0; jj < JB; ++jj)
                acc[jj] = fmaf(xv, Wx[(size_t)jj * HDIM + k], acc[jj]);
        }
    }

    // ---- recurrent part: wave wv covers k in [wv*128, (wv+1)*128) ----
    {
        const int k0 = wv * HKW;
        #pragma unroll 8
        for (int k = k0; k < k0 + HKW; ++k) {
            const float hv = hR[(size_t)k * BATCH + b];  // coalesced 256B/wave
            #pragma unroll
            for (int jj = 0; jj < JB; ++jj)
                acc[jj] = fmaf(hv, Wh[(size_t)jj * HDIM + k], acc[jj]);
        }
    }

    // ---- cross-wave reduction ----
    #pragma unroll
    for (int jj = 0; jj < JB; ++jj)
        red[(wv * JB + jj) * RSTR + b] = acc[jj];       // stride-1: conflict-free
    __syncthreads();

    const int b2  = tid >> 3;          // 8 consecutive lanes share b2
    const int jj2 = tid & 7;
    float s = 0.0f;
    #pragma unroll
    for (int w2 = 0; w2 < NWAVE; ++w2)
        s += red[(w2 * JB + jj2) * RSTR + b2];          // 2-way max (free)

    const int j = blk * JB + jj2;
    const float hold = hR[(size_t)j * BATCH + b2];
    const float hnew = 0.5f * hold + 0.5f * tanhf(s);
    hW[(size_t)j * BATCH + b2] = hnew;
    out[((size_t)((size_t)t * BATCH + b2) * 2 + layer) * HDIM + j] = hnew;
}

extern "C" void kernel_launch(void* const* d_in, const int* in_sizes, int n_in,
                              void* d_out, int out_size, void* d_ws, size_t ws_size,
                              hipStream_t stream) {
    const float* x    = (const float*)d_in[0];
    const float* Wi0  = (const float*)d_in[1];
    const float* Wh0  = (const float*)d_in[2];
    const float* Wi1  = (const float*)d_in[3];
    const float* Wh1  = (const float*)d_in[4];
    float* out = (float*)d_out;
    float* ws  = (float*)d_ws;

    init_ws_kernel<<<64, 256, 0, stream>>>(ws);
    for (int i = 0; i <= TSTEPS; ++i) {
        step_kernel<<<2 * NBLK, 512, 0, stream>>>(i, x, Wi0, Wh0, Wi1, Wh1, out, ws);
    }
}